// Round 1
// 1024.794 us; speedup vs baseline: 1.0385x; 1.0385x over previous
//
#include <hip/hip_runtime.h>

#define NEG_SLOPE 0.2f

// ---------------- CSR build: ONE atomic pass records count + local position
__global__ void hist_k(const int* __restrict__ dst, int* __restrict__ counts,
                       int* __restrict__ pos, int E) {
    int i = blockIdx.x * blockDim.x + threadIdx.x;
    if (i < E) pos[i] = atomicAdd(&counts[dst[i]], 1);
}

__global__ __launch_bounds__(256) void scan_blocks(const int* __restrict__ in,
                                                   int* __restrict__ part,
                                                   int* __restrict__ aux, int n) {
    __shared__ int wsum[4];
    int t = threadIdx.x;
    int lane = t & 63;
    int w = t >> 6;
    int base = blockIdx.x * 1024 + t * 4;
    int c[4];
#pragma unroll
    for (int i = 0; i < 4; ++i) c[i] = (base + i < n) ? in[base + i] : 0;
    int tsum = c[0] + c[1] + c[2] + c[3];
    int incl = tsum;
#pragma unroll
    for (int d = 1; d < 64; d <<= 1) {
        int v = __shfl_up(incl, d, 64);
        if (lane >= d) incl += v;
    }
    if (lane == 63) wsum[w] = incl;
    __syncthreads();
    int wpre = 0;
    for (int i = 0; i < w; ++i) wpre += wsum[i];
    int run = wpre + incl - tsum;   // exclusive prefix for this thread
#pragma unroll
    for (int i = 0; i < 4; ++i) {
        if (base + i < n) part[base + i] = run;
        run += c[i];
    }
    if (t == 255) aux[blockIdx.x] = run;  // block total
}

__global__ void scan_aux_k(int* __restrict__ aux, int* __restrict__ offs, int nblk, int N) {
    int t = threadIdx.x;  // blockDim = 64, nblk <= 64
    int v = (t < nblk) ? aux[t] : 0;
    int incl = v;
#pragma unroll
    for (int d = 1; d < 64; d <<= 1) {
        int u = __shfl_up(incl, d, 64);
        if (t >= d) incl += u;
    }
    if (t < nblk) aux[t] = incl - v;  // exclusive
    if (t == 63) offs[N] = incl;      // grand total == E
}

__global__ void scan_add_k(int* __restrict__ offs, const int* __restrict__ aux, int n) {
    int i = blockIdx.x * blockDim.x + threadIdx.x;
    if (i < n) offs[i] += aux[i >> 10];
}

// ------------------------------------------- fold ae into w_e (tiny, 1 block)
__global__ void prep_we(const float* __restrict__ ae1, const float* __restrict__ we1,
                        const float* __restrict__ ae2, const float* __restrict__ we2,
                        float* __restrict__ wec) {
    int t = threadIdx.x;  // 320 threads
    if (t < 256) {
        int h = t >> 6, c = t & 63;
        float s = 0.f;
        for (int f = 0; f < 32; ++f) s = fmaf(ae1[h * 32 + f], we1[(h * 32 + f) * 64 + c], s);
        wec[h * 64 + c] = s;
    } else if (t < 320) {
        int c = t - 256;
        float s = 0.f;
        for (int f = 0; f < 64; ++f) s = fmaf(ae2[f], we2[f * 64 + c], s);
        wec[256 + c] = s;
    }
}

// --- single pass over edge_attr; CSR slot computed inline (offs[dst]+pos).
// 16 lanes cooperate on one edge: lane l reads ea[quad*256 + l*4] (float4) so a
// wave's load instruction is 1 KiB fully contiguous (4 edge rows). Weight
// fragments (5 heads x 4 floats) live in registers; per-edge dots finish with
// a 4-round shfl_xor butterfly inside each 16-lane group. 4 quads unrolled per
// wave iteration for memory-level parallelism.
__global__ __launch_bounds__(256) void edge_proj_csr(const float* __restrict__ ea,
                                                     const float* __restrict__ wec,
                                                     const float* __restrict__ eh1,
                                                     const int* __restrict__ src,
                                                     const int* __restrict__ dst,
                                                     const int* __restrict__ pos,
                                                     const int* __restrict__ offs,
                                                     float* __restrict__ pe1,
                                                     float* __restrict__ ee2c,
                                                     int* __restrict__ esrc, int E) {
    int l = threadIdx.x & 63;
    int li = l & 15;            // column-chunk within edge (16 B each)
    int eg = l >> 4;            // which of the 4 edges in this quad
    int wid = (blockIdx.x * blockDim.x + threadIdx.x) >> 6;  // global wave id
    int nw = (gridDim.x * blockDim.x) >> 6;
    // weights in registers: w[h][li*4 .. li*4+4)
    float4 w0 = *(const float4*)(wec + 0 * 64 + li * 4);
    float4 w1 = *(const float4*)(wec + 1 * 64 + li * 4);
    float4 w2 = *(const float4*)(wec + 2 * 64 + li * 4);
    float4 w3 = *(const float4*)(wec + 3 * 64 + li * 4);
    float4 w4 = *(const float4*)(wec + 4 * 64 + li * 4);
    int nq = (E + 3) >> 2;  // quads of 4 edges
    for (int q0 = wid * 4; q0 < nq; q0 += nw * 4) {
        float4 v[4];
        int e[4];
#pragma unroll
        for (int u = 0; u < 4; ++u) {
            e[u] = (q0 + u) * 4 + eg;
            v[u] = make_float4(0.f, 0.f, 0.f, 0.f);
            if (e[u] < E) v[u] = *(const float4*)(ea + (size_t)e[u] * 64 + li * 4);
        }
#pragma unroll
        for (int u = 0; u < 4; ++u) {
            float4 vv = v[u];
            float d0 = fmaf(vv.x, w0.x, fmaf(vv.y, w0.y, fmaf(vv.z, w0.z, vv.w * w0.w)));
            float d1 = fmaf(vv.x, w1.x, fmaf(vv.y, w1.y, fmaf(vv.z, w1.z, vv.w * w1.w)));
            float d2 = fmaf(vv.x, w2.x, fmaf(vv.y, w2.y, fmaf(vv.z, w2.z, vv.w * w2.w)));
            float d3 = fmaf(vv.x, w3.x, fmaf(vv.y, w3.y, fmaf(vv.z, w3.z, vv.w * w3.w)));
            float d4 = fmaf(vv.x, w4.x, fmaf(vv.y, w4.y, fmaf(vv.z, w4.z, vv.w * w4.w)));
#pragma unroll
            for (int m = 1; m < 16; m <<= 1) {
                d0 += __shfl_xor(d0, m, 64);
                d1 += __shfl_xor(d1, m, 64);
                d2 += __shfl_xor(d2, m, 64);
                d3 += __shfl_xor(d3, m, 64);
                d4 += __shfl_xor(d4, m, 64);
            }
            if (li == 0 && e[u] < E) {
                int ee = e[u];
                int s = src[ee];
                int p = offs[dst[ee]] + pos[ee];
                float4 ehv = *(const float4*)(eh1 + (size_t)s * 4);
                *(float4*)(pe1 + (size_t)p * 4) =
                    make_float4(d0 + ehv.x, d1 + ehv.y, d2 + ehv.z, d3 + ehv.w);
                ee2c[p] = d4;
                esrc[p] = s;
            }
        }
    }
}

// ------------------------------------------------- node GEMM: out = X @ W^T
template <int M>
__global__ __launch_bounds__(256) void gemm_nodes(const float* __restrict__ X,
                                                  const float* __restrict__ W,
                                                  float* __restrict__ out, int N) {
    const int K = 128, KC = 64, NT = 64;
    __shared__ float xs[NT][KC + 1];
    __shared__ float ws[KC][M + 1];
    const int CT = M / 8;
    const int NG = 256 / CT;
    const int NPT = NT / NG;
    int t = threadIdx.x;
    int tc = t % CT, tn = t / CT;
    int nb = blockIdx.x * NT;
    float acc[NPT][8];
#pragma unroll
    for (int i = 0; i < NPT; ++i)
#pragma unroll
        for (int j = 0; j < 8; ++j) acc[i][j] = 0.f;

    for (int kc = 0; kc < K; kc += KC) {
        for (int i = t * 4; i < M * KC; i += 1024) {
            int m = i / KC, k = i % KC;
            float4 v = *(const float4*)(W + (size_t)m * K + kc + k);
            ws[k][m] = v.x; ws[k + 1][m] = v.y; ws[k + 2][m] = v.z; ws[k + 3][m] = v.w;
        }
        for (int i = t * 4; i < NT * KC; i += 1024) {
            int r = i / KC, k = i % KC;
            int n = nb + r;
            float4 v = make_float4(0.f, 0.f, 0.f, 0.f);
            if (n < N) v = *(const float4*)(X + (size_t)n * K + kc + k);
            xs[r][k] = v.x; xs[r][k + 1] = v.y; xs[r][k + 2] = v.z; xs[r][k + 3] = v.w;
        }
        __syncthreads();
#pragma unroll 4
        for (int k = 0; k < KC; ++k) {
            float wv[8];
            *(float4*)&wv[0] = *(const float4*)&ws[k][tc * 8];
            *(float4*)&wv[4] = *(const float4*)&ws[k][tc * 8 + 4];
#pragma unroll
            for (int i = 0; i < NPT; ++i) {
                float xv = xs[tn * NPT + i][k];
#pragma unroll
                for (int j = 0; j < 8; ++j) acc[i][j] = fmaf(xv, wv[j], acc[i][j]);
            }
        }
        __syncthreads();
    }
#pragma unroll
    for (int i = 0; i < NPT; ++i) {
        int n = nb + tn * NPT + i;
        if (n < N) {
            *(float4*)(out + (size_t)n * M + tc * 8) =
                make_float4(acc[i][0], acc[i][1], acc[i][2], acc[i][3]);
            *(float4*)(out + (size_t)n * M + tc * 8 + 4) =
                make_float4(acc[i][4], acc[i][5], acc[i][6], acc[i][7]);
        }
    }
}

// ----------------------------------- eh/et: per (node,head) dot with ah / at
template <int H, int F>
__global__ void ehet(const float* __restrict__ feat, const float* __restrict__ ah,
                     const float* __restrict__ at, float* __restrict__ eh,
                     float* __restrict__ et, int N) {
    int i = blockIdx.x * blockDim.x + threadIdx.x;  // i = n*H + h
    if (i >= N * H) return;
    int h = i % H;
    const float* f = feat + (size_t)i * F;
    float sh = 0.f, st = 0.f;
#pragma unroll
    for (int j = 0; j < F; j += 4) {
        float4 v = *(const float4*)(f + j);
        float4 a = *(const float4*)(ah + h * F + j);
        float4 b = *(const float4*)(at + h * F + j);
        sh += v.x * a.x + v.y * a.y + v.z * a.z + v.w * a.w;
        st += v.x * b.x + v.y * b.y + v.z * b.z + v.w * b.w;
    }
    eh[i] = sh;
    et[i] = st;
}

// --------- layer-1 softmax+aggregate: one wave/node, H=4, F=32, relu output
// single-phase (scores are O(1); exp cannot overflow), 8 edge-groups x 8 lanes
// each lane owns 16 cols (4 float4) of one of 8 rows in flight
__global__ __launch_bounds__(256) void agg1(const float* __restrict__ feat,
                                            const float* __restrict__ pe1,
                                            const float* __restrict__ et,
                                            const int* __restrict__ offs,
                                            const int* __restrict__ esrc,
                                            const float* __restrict__ bias,
                                            float* __restrict__ out, int N) {
    int n = (blockIdx.x * blockDim.x + threadIdx.x) >> 6;
    int l = threadIdx.x & 63;
    if (n >= N) return;
    int start = offs[n], end = offs[n + 1];
    int eg = l >> 3, li = l & 7, h = li >> 1;
    float etv = et[n * 4 + h];

    float s = 0.f;
    float4 a0 = make_float4(0.f, 0.f, 0.f, 0.f);
    float4 a1 = a0, a2 = a0, a3 = a0;
    for (int j0 = start; j0 < end; j0 += 8) {
        int j = j0 + eg;
        if (j < end) {
            int sv = esrc[j];
            float x = pe1[(size_t)j * 4 + h] + etv;
            x = x > 0.f ? x : NEG_SLOPE * x;
            float wgt = __expf(x);
            s += wgt;
            const float4* fr = (const float4*)(feat + (size_t)sv * 128 + li * 16);
            float4 v0 = fr[0], v1 = fr[1], v2 = fr[2], v3 = fr[3];
            a0.x = fmaf(wgt, v0.x, a0.x); a0.y = fmaf(wgt, v0.y, a0.y);
            a0.z = fmaf(wgt, v0.z, a0.z); a0.w = fmaf(wgt, v0.w, a0.w);
            a1.x = fmaf(wgt, v1.x, a1.x); a1.y = fmaf(wgt, v1.y, a1.y);
            a1.z = fmaf(wgt, v1.z, a1.z); a1.w = fmaf(wgt, v1.w, a1.w);
            a2.x = fmaf(wgt, v2.x, a2.x); a2.y = fmaf(wgt, v2.y, a2.y);
            a2.z = fmaf(wgt, v2.z, a2.z); a2.w = fmaf(wgt, v2.w, a2.w);
            a3.x = fmaf(wgt, v3.x, a3.x); a3.y = fmaf(wgt, v3.y, a3.y);
            a3.z = fmaf(wgt, v3.z, a3.z); a3.w = fmaf(wgt, v3.w, a3.w);
        }
    }
#pragma unroll
    for (int d = 8; d < 64; d <<= 1) {
        s += __shfl_xor(s, d);
        a0.x += __shfl_xor(a0.x, d); a0.y += __shfl_xor(a0.y, d);
        a0.z += __shfl_xor(a0.z, d); a0.w += __shfl_xor(a0.w, d);
        a1.x += __shfl_xor(a1.x, d); a1.y += __shfl_xor(a1.y, d);
        a1.z += __shfl_xor(a1.z, d); a1.w += __shfl_xor(a1.w, d);
        a2.x += __shfl_xor(a2.x, d); a2.y += __shfl_xor(a2.y, d);
        a2.z += __shfl_xor(a2.z, d); a2.w += __shfl_xor(a2.w, d);
        a3.x += __shfl_xor(a3.x, d); a3.y += __shfl_xor(a3.y, d);
        a3.w += __shfl_xor(a3.w, d); a3.z += __shfl_xor(a3.z, d);
    }
    if (eg == 0) {
        float inv = s > 0.f ? 1.f / s : 0.f;
        const float4* bp = (const float4*)(bias + li * 16);
        float4 b0 = bp[0], b1 = bp[1], b2 = bp[2], b3 = bp[3];
        float4* op = (float4*)(out + (size_t)n * 128 + li * 16);
        op[0] = make_float4(fmaxf(a0.x * inv + b0.x, 0.f), fmaxf(a0.y * inv + b0.y, 0.f),
                            fmaxf(a0.z * inv + b0.z, 0.f), fmaxf(a0.w * inv + b0.w, 0.f));
        op[1] = make_float4(fmaxf(a1.x * inv + b1.x, 0.f), fmaxf(a1.y * inv + b1.y, 0.f),
                            fmaxf(a1.z * inv + b1.z, 0.f), fmaxf(a1.w * inv + b1.w, 0.f));
        op[2] = make_float4(fmaxf(a2.x * inv + b2.x, 0.f), fmaxf(a2.y * inv + b2.y, 0.f),
                            fmaxf(a2.z * inv + b2.z, 0.f), fmaxf(a2.w * inv + b2.w, 0.f));
        op[3] = make_float4(fmaxf(a3.x * inv + b3.x, 0.f), fmaxf(a3.y * inv + b3.y, 0.f),
                            fmaxf(a3.z * inv + b3.z, 0.f), fmaxf(a3.w * inv + b3.w, 0.f));
    }
}

// --------- layer-2 softmax+aggregate: one wave/node, H=1, F=64, no relu
__global__ __launch_bounds__(256) void agg2(const float* __restrict__ feat,
                                            const float* __restrict__ ee2c,
                                            const float* __restrict__ eh2,
                                            const float* __restrict__ et2,
                                            const int* __restrict__ offs,
                                            const int* __restrict__ esrc,
                                            const float* __restrict__ bias,
                                            float* __restrict__ out, int N) {
    int n = (blockIdx.x * blockDim.x + threadIdx.x) >> 6;
    int l = threadIdx.x & 63;
    if (n >= N) return;
    int start = offs[n], end = offs[n + 1];
    int eg = l >> 3, li = l & 7;
    float etv = et2[n];

    float s = 0.f;
    float4 a0 = make_float4(0.f, 0.f, 0.f, 0.f);
    float4 a1 = a0;
    for (int j0 = start; j0 < end; j0 += 8) {
        int j = j0 + eg;
        if (j < end) {
            int sv = esrc[j];
            float x = eh2[sv] + ee2c[j] + etv;
            x = x > 0.f ? x : NEG_SLOPE * x;
            float wgt = __expf(x);
            s += wgt;
            const float4* fr = (const float4*)(feat + (size_t)sv * 64 + li * 8);
            float4 v0 = fr[0], v1 = fr[1];
            a0.x = fmaf(wgt, v0.x, a0.x); a0.y = fmaf(wgt, v0.y, a0.y);
            a0.z = fmaf(wgt, v0.z, a0.z); a0.w = fmaf(wgt, v0.w, a0.w);
            a1.x = fmaf(wgt, v1.x, a1.x); a1.y = fmaf(wgt, v1.y, a1.y);
            a1.z = fmaf(wgt, v1.z, a1.z); a1.w = fmaf(wgt, v1.w, a1.w);
        }
    }
#pragma unroll
    for (int d = 8; d < 64; d <<= 1) {
        s += __shfl_xor(s, d);
        a0.x += __shfl_xor(a0.x, d); a0.y += __shfl_xor(a0.y, d);
        a0.z += __shfl_xor(a0.z, d); a0.w += __shfl_xor(a0.w, d);
        a1.x += __shfl_xor(a1.x, d); a1.y += __shfl_xor(a1.y, d);
        a1.z += __shfl_xor(a1.z, d); a1.w += __shfl_xor(a1.w, d);
    }
    if (eg == 0) {
        float inv = s > 0.f ? 1.f / s : 0.f;
        const float4* bp = (const float4*)(bias + li * 8);
        float4 b0 = bp[0], b1 = bp[1];
        float4* op = (float4*)(out + (size_t)n * 64 + li * 8);
        op[0] = make_float4(a0.x * inv + b0.x, a0.y * inv + b0.y,
                            a0.z * inv + b0.z, a0.w * inv + b0.w);
        op[1] = make_float4(a1.x * inv + b1.x, a1.y * inv + b1.y,
                            a1.z * inv + b1.z, a1.w * inv + b1.w);
    }
}

// ---------------------------------------------------------------------------
extern "C" void kernel_launch(void* const* d_in, const int* in_sizes, int n_in,
                              void* d_out, int out_size, void* d_ws, size_t ws_size,
                              hipStream_t stream) {
    const float* x    = (const float*)d_in[0];
    const float* ea   = (const float*)d_in[1];
    const int*   src  = (const int*)d_in[2];
    const int*   dst  = (const int*)d_in[3];
    const float* wfc1 = (const float*)d_in[4];
    const float* we1  = (const float*)d_in[5];
    const float* ah1  = (const float*)d_in[6];
    const float* ae1  = (const float*)d_in[7];
    const float* at1  = (const float*)d_in[8];
    const float* b1   = (const float*)d_in[9];
    const float* wfc2 = (const float*)d_in[10];
    const float* we2  = (const float*)d_in[11];
    const float* ah2  = (const float*)d_in[12];
    const float* ae2  = (const float*)d_in[13];
    const float* at2  = (const float*)d_in[14];
    const float* b2   = (const float*)d_in[15];
    const int N = in_sizes[0] / 128;
    const int E = in_sizes[2];
    float* out = (float*)d_out;

    char* p = (char*)d_ws;
    auto alloc = [&](size_t bytes) -> void* {
        void* r = (void*)p;
        p += (bytes + 255) & ~(size_t)255;
        return r;
    };
    int*   counts = (int*)alloc((size_t)N * 4);
    int*   offs   = (int*)alloc(((size_t)N + 1) * 4);
    int*   aux    = (int*)alloc(64 * 4);
    int*   pos    = (int*)alloc((size_t)E * 4);
    float* wec    = (float*)alloc(320 * 4);
    float* pe1    = (float*)alloc((size_t)E * 4 * 4);
    float* ee2c   = (float*)alloc((size_t)E * 4);
    int*   esrc   = (int*)alloc((size_t)E * 4);
    float* feat1  = (float*)alloc((size_t)N * 128 * 4);
    float* eh1    = (float*)alloc((size_t)N * 4 * 4);
    float* et1    = (float*)alloc((size_t)N * 4 * 4);
    float* h1     = (float*)alloc((size_t)N * 128 * 4);
    float* feat2  = (float*)alloc((size_t)N * 64 * 4);
    float* eh2    = (float*)alloc((size_t)N * 4);
    float* et2    = (float*)alloc((size_t)N * 4);

    int ebl = (E + 255) / 256;
    int nblk = (N + 1023) / 1024;

    // CSR build: one atomic pass + scans (rank = offs[dst]+pos, computed inline later)
    hipMemsetAsync(counts, 0, (size_t)N * 4, stream);
    hist_k<<<ebl, 256, 0, stream>>>(dst, counts, pos, E);
    scan_blocks<<<nblk, 256, 0, stream>>>(counts, offs, aux, N);
    scan_aux_k<<<1, 64, 0, stream>>>(aux, offs, nblk, N);
    scan_add_k<<<(N + 255) / 256, 256, 0, stream>>>(offs, aux, N);

    // layer-1 node path (needed before edge_proj_csr folds eh1 in)
    gemm_nodes<128><<<(N + 63) / 64, 256, 0, stream>>>(x, wfc1, feat1, N);
    ehet<4, 32><<<(N * 4 + 255) / 256, 256, 0, stream>>>(feat1, ah1, at1, eh1, et1, N);

    // edge path: one pass over edge_attr, results land in CSR order
    prep_we<<<1, 320, 0, stream>>>(ae1, we1, ae2, we2, wec);
    edge_proj_csr<<<4096, 256, 0, stream>>>(ea, wec, eh1, src, dst, pos, offs,
                                            pe1, ee2c, esrc, E);

    agg1<<<(N + 3) / 4, 256, 0, stream>>>(feat1, pe1, et1, offs, esrc, b1, h1, N);

    gemm_nodes<64><<<(N + 63) / 64, 256, 0, stream>>>(h1, wfc2, feat2, N);
    ehet<1, 64><<<(N + 255) / 256, 256, 0, stream>>>(feat2, ah2, at2, eh2, et2, N);
    agg2<<<(N + 3) / 4, 256, 0, stream>>>(feat2, ee2c, eh2, et2, offs, esrc, b2, out, N);
}